// Round 3
// baseline (213.952 us; speedup 1.0000x reference)
//
#include <hip/hip_runtime.h>

typedef __attribute__((ext_vector_type(8))) short short8;
typedef __attribute__((ext_vector_type(4))) float f32x4;

#define SCALE2 0.06375871571f   // (1/sqrt(512)) * log2(e)

__device__ __forceinline__ float bfu(unsigned short u){
  return __uint_as_float(((unsigned int)u) << 16);
}
__device__ __forceinline__ unsigned short f2b(float x){   // RNE
  unsigned int b = __float_as_uint(x);
  return (unsigned short)((b + 0x7fffu + ((b>>16)&1u)) >> 16);
}
// 8 contiguous f32 -> 8 bf16 packed in a uint4
__device__ __forceinline__ uint4 pack8(const float* f){
  float4 a = *(const float4*)f, b = *(const float4*)(f+4);
  uint4 r;
  r.x = (unsigned)f2b(a.x) | ((unsigned)f2b(a.y)<<16);
  r.y = (unsigned)f2b(a.z) | ((unsigned)f2b(a.w)<<16);
  r.z = (unsigned)f2b(b.x) | ((unsigned)f2b(b.y)<<16);
  r.w = (unsigned)f2b(b.z) | ((unsigned)f2b(b.w)<<16);
  return r;
}

// ---------------- fused input prep: weight transpose + q/k convert ----------------
__global__ __launch_bounds__(256) void prep_inputs(
    const float* Wq, const float* Wk, const float* Wv, const float* Wo,
    const float* q, const float* k, unsigned short* wt, unsigned short* qk_dst)
{
  const int id = blockIdx.x, t = threadIdx.x;
  if (id < 256){
    const int m = id >> 6;
    const float* W = (m==0)?Wq:(m==1)?Wk:(m==2)?Wv:Wo;
    unsigned short* dst = wt + (long)m*262144;
    __shared__ unsigned short tile[64][72];
    const int n0 = ((id>>3)&7)*64, k0 = (id&7)*64;
    {
      int r = t>>2, c0 = (t&3)*16;
      uint4 u0 = pack8(W + (long)(k0+r)*512 + n0 + c0);
      uint4 u1 = pack8(W + (long)(k0+r)*512 + n0 + c0 + 8);
      unsigned short* us0 = (unsigned short*)&u0;
      unsigned short* us1 = (unsigned short*)&u1;
      #pragma unroll
      for (int i=0;i<8;++i) tile[c0+i][r] = us0[i];
      #pragma unroll
      for (int i=0;i<8;++i) tile[c0+8+i][r] = us1[i];
    }
    __syncthreads();
    {
      int n = t>>2, ks = (t&3)*16;
      *(uint4*)(dst + (long)(n0+n)*512 + k0 + ks)     = *(uint4*)&tile[n][ks];
      *(uint4*)(dst + (long)(n0+n)*512 + k0 + ks + 8) = *(uint4*)&tile[n][ks+8];
    }
  } else {
    long i = ((long)(id-256)*256 + t)*8;
    const float* src = (i < 4194304) ? q + i : k + (i - 4194304);
    *(uint4*)(qk_dst + i) = pack8(src);
  }
}

// ---------------- QKV projection (bf16 MFMA, dbuf LDS, 1 barrier/iter) ----------------
__global__ __launch_bounds__(256) void proj_mfma(
    const unsigned short* qin, const unsigned short* kin, const unsigned short* wt,
    const float* bq, const float* bk, const float* bv,
    unsigned short* q_bf, unsigned short* k_bf, unsigned short* vt_bf)
{
  const int mat = blockIdx.z;
  const unsigned short* A = (mat==0)? qin : kin;
  const unsigned short* Wt = wt + (long)mat*262144;
  const float* bias = (mat==0)?bq:(mat==1)?bk:bv;
  const int row0 = blockIdx.y*128, col0 = blockIdx.x*128;
  __shared__ unsigned short As[2][128][40];
  __shared__ unsigned short Ws[2][128][40];
  const int t = threadIdx.x;
  const int lane = t & 63, wid = t >> 6;
  const int ln = lane & 15, quad = lane >> 4;
  const int wy = wid >> 1, wx = wid & 1;
  f32x4 acc[4][4];
  #pragma unroll
  for (int i=0;i<4;++i){
    #pragma unroll
    for (int j=0;j<4;++j) acc[i][j] = (f32x4){0.f,0.f,0.f,0.f};
  }
  const int sr = t>>1, sk0 = (t&1)*16;
  const unsigned short* Arow = A  + (long)(row0+sr)*512 + sk0;
  const unsigned short* Wrow = Wt + (long)(col0+sr)*512 + sk0;
  uint4 a0 = *(const uint4*)(Arow);
  uint4 a1 = *(const uint4*)(Arow + 8);
  uint4 w0 = *(const uint4*)(Wrow);
  uint4 w1 = *(const uint4*)(Wrow + 8);
  *(uint4*)&As[0][sr][sk0]   = a0;
  *(uint4*)&As[0][sr][sk0+8] = a1;
  *(uint4*)&Ws[0][sr][sk0]   = w0;
  *(uint4*)&Ws[0][sr][sk0+8] = w1;
  __syncthreads();
  for (int it=0; it<16; ++it){
    const int cur = it & 1;
    if (it < 15){
      a0 = *(const uint4*)(Arow + (it+1)*32);
      a1 = *(const uint4*)(Arow + (it+1)*32 + 8);
      w0 = *(const uint4*)(Wrow + (it+1)*32);
      w1 = *(const uint4*)(Wrow + (it+1)*32 + 8);
    }
    short8 a[4], b[4];
    #pragma unroll
    for (int mt=0;mt<4;++mt) a[mt] = *(const short8*)&As[cur][wy*64+mt*16+ln][quad*8];
    #pragma unroll
    for (int nt=0;nt<4;++nt) b[nt] = *(const short8*)&Ws[cur][wx*64+nt*16+ln][quad*8];
    #pragma unroll
    for (int mt=0;mt<4;++mt){
      #pragma unroll
      for (int nt=0;nt<4;++nt)
        acc[mt][nt] = __builtin_amdgcn_mfma_f32_16x16x32_bf16(a[mt], b[nt], acc[mt][nt], 0,0,0);
    }
    if (it < 15){
      *(uint4*)&As[cur^1][sr][sk0]   = a0;
      *(uint4*)&As[cur^1][sr][sk0+8] = a1;
      *(uint4*)&Ws[cur^1][sr][sk0]   = w0;
      *(uint4*)&Ws[cur^1][sr][sk0+8] = w1;
    }
    __syncthreads();
  }
  float bias_v[4];
  #pragma unroll
  for (int nt=0;nt<4;++nt) bias_v[nt] = bias[col0 + wx*64 + nt*16 + ln];
  if (mat < 2){
    unsigned short* dst = (mat==0)? q_bf : k_bf;
    #pragma unroll
    for (int mt=0;mt<4;++mt){
      int row = row0 + wy*64 + mt*16 + quad*4;
      #pragma unroll
      for (int nt=0;nt<4;++nt){
        int col = col0 + wx*64 + nt*16 + ln;
        #pragma unroll
        for (int r=0;r<4;++r)
          dst[(long)(row+r)*512 + col] = f2b(acc[mt][nt][r] + bias_v[nt]);
      }
    }
  } else {
    #pragma unroll
    for (int mt=0;mt<4;++mt){
      int row = row0 + wy*64 + mt*16 + quad*4;   // token base, 4-aligned
      int bb = row >> 10, sk = row & 1023;
      #pragma unroll
      for (int nt=0;nt<4;++nt){
        int col = col0 + wx*64 + nt*16 + ln;
        int h = col >> 6, dd = col & 63;
        uint2 pk2; unsigned short* pp = (unsigned short*)&pk2;
        #pragma unroll
        for (int r=0;r<4;++r) pp[r] = f2b(acc[mt][nt][r] + bias_v[nt]);
        *(uint2*)(vt_bf + (((long)((bb*8+h)*64+dd)) << 10) + sk) = pk2;
      }
    }
  }
}

// ---------------- flash attention: swapped QK^T, vectorized LDS P, 64 q-rows/block ----------------
// Each wave owns 16 q-rows (q = wid*16 + ln, lane-local). S^T via mfma(K,Q): lane holds
// S[k = kt*16+quad*4+r][q = ln] (same empirically-validated C/D mapping as the passing
// kernel, A/B roles swapped). Softmax fully in-register (av/mval per-lane scalars).
// P written to wave-private row-major P[q][k] LDS with 4x ds_write_b64 (4 consecutive k
// per reg pair, true k columns) and read back with the standard A-fragment pattern —
// the same P-at-true-k-columns + pattern-matched V load that made round-0 correct.
__global__ __launch_bounds__(256, 3) void attn_mfma(
    const unsigned short* q_bf, const unsigned short* k_bf, const unsigned short* vt_bf,
    const float* pres_q, const float* pres_k, unsigned short* o_bf)
{
  const int bx = blockIdx.x;
  const int b = bx >> 3, h = bx & 7;
  const int q0 = blockIdx.y * 64;
  const int t = threadIdx.x;
  const int lane = t & 63, wid = t >> 6, ln = lane & 15, quad = lane >> 4;
  __shared__ unsigned short Ks[2][64][72];
  __shared__ unsigned short Vt[2][64][72];
  __shared__ unsigned short Pw[4][16][72];
  __shared__ float pk_s[2][64];
  {
    int tok = t>>2, ds = (t&3)*16;
    const unsigned short* sk = k_bf + (long)(b*1024 + tok)*512 + h*64 + ds;
    *(uint4*)&Ks[0][tok][ds]   = *(const uint4*)sk;
    *(uint4*)&Ks[0][tok][ds+8] = *(const uint4*)(sk+8);
    const unsigned short* sv = vt_bf + (((long)((b*8+h)*64 + tok)) << 10) + ds;
    *(uint4*)&Vt[0][tok][ds]   = *(const uint4*)sv;
    *(uint4*)&Vt[0][tok][ds+8] = *(const uint4*)(sv+8);
  }
  if (t < 64) pk_s[0][t] = pres_k[b*1024 + t];
  // Q fragments direct from global (once): rows q0 + wid*16 + ln
  const unsigned short* qrow = q_bf + (long)(b*1024 + q0 + wid*16 + ln)*512 + h*64;
  short8 aq0 = *(const short8*)(qrow + quad*8);
  short8 aq1 = *(const short8*)(qrow + 32 + quad*8);
  const float av = SCALE2 * pres_q[b*1024 + q0 + wid*16 + ln];
  const float mval = (av == 0.f) ? 0.f : -43.f;
  f32x4 oacc[4];
  #pragma unroll
  for (int i=0;i<4;++i) oacc[i] = (f32x4){0.f,0.f,0.f,0.f};
  float lsum = 0.f;
  __syncthreads();

  for (int it=0; it<16; ++it){
    const int cur = it & 1;
    const int k0n = (it+1)*64;
    uint4 pf_k0, pf_k1, pf_v0, pf_v1; float pf_p = 0.f;
    if (it < 15){
      int tok = t>>2, ds = (t&3)*16;
      const unsigned short* sk = k_bf + (long)(b*1024 + k0n + tok)*512 + h*64 + ds;
      pf_k0 = *(const uint4*)sk;
      pf_k1 = *(const uint4*)(sk+8);
      const unsigned short* sv = vt_bf + (((long)((b*8+h)*64 + tok)) << 10) + k0n + ds;
      pf_v0 = *(const uint4*)sv;
      pf_v1 = *(const uint4*)(sv+8);
      if (t < 64) pf_p = pres_k[b*1024 + k0n + t];
    }
    // S^T = K Q^T : lane holds S[k = kt*16+quad*4+r][q = wid*16+ln]
    f32x4 sc[4];
    #pragma unroll
    for (int kt=0;kt<4;++kt) sc[kt] = (f32x4){0.f,0.f,0.f,0.f};
    __builtin_amdgcn_s_setprio(1);
    #pragma unroll
    for (int kt=0;kt<4;++kt){
      short8 kb0 = *(const short8*)&Ks[cur][kt*16+ln][quad*8];
      short8 kb1 = *(const short8*)&Ks[cur][kt*16+ln][32+quad*8];
      sc[kt] = __builtin_amdgcn_mfma_f32_16x16x32_bf16(kb0, aq0, sc[kt], 0,0,0);
      sc[kt] = __builtin_amdgcn_mfma_f32_16x16x32_bf16(kb1, aq1, sc[kt], 0,0,0);
    }
    __builtin_amdgcn_s_setprio(0);
    // softmax: x = pk*(s*av - mval) + mval ; e = 2^x ; pack 4 consecutive k -> b64 write
    #pragma unroll
    for (int kt=0;kt<4;++kt){
      float4 pk4 = *(const float4*)&pk_s[cur][kt*16 + quad*4];
      float x0 = __builtin_fmaf(pk4.x, __builtin_fmaf(sc[kt][0], av, -mval), mval);
      float x1 = __builtin_fmaf(pk4.y, __builtin_fmaf(sc[kt][1], av, -mval), mval);
      float x2 = __builtin_fmaf(pk4.z, __builtin_fmaf(sc[kt][2], av, -mval), mval);
      float x3 = __builtin_fmaf(pk4.w, __builtin_fmaf(sc[kt][3], av, -mval), mval);
      float e0 = __builtin_amdgcn_exp2f(x0);
      float e1 = __builtin_amdgcn_exp2f(x1);
      float e2 = __builtin_amdgcn_exp2f(x2);
      float e3 = __builtin_amdgcn_exp2f(x3);
      lsum += (e0+e1)+(e2+e3);
      uint2 w;
      w.x = (unsigned)f2b(e0) | ((unsigned)f2b(e1)<<16);
      w.y = (unsigned)f2b(e2) | ((unsigned)f2b(e3)<<16);
      *(uint2*)&Pw[wid][ln][kt*16 + quad*4] = w;
    }
    // O += P V : A-fragment read of wave-private P (same pattern as K/V loads)
    short8 ap0 = *(const short8*)&Pw[wid][ln][quad*8];
    short8 ap1 = *(const short8*)&Pw[wid][ln][32 + quad*8];
    __builtin_amdgcn_s_setprio(1);
    #pragma unroll
    for (int dt=0;dt<4;++dt){
      short8 vb0 = *(const short8*)&Vt[cur][dt*16+ln][quad*8];
      short8 vb1 = *(const short8*)&Vt[cur][dt*16+ln][32+quad*8];
      oacc[dt] = __builtin_amdgcn_mfma_f32_16x16x32_bf16(ap0, vb0, oacc[dt], 0,0,0);
      oacc[dt] = __builtin_amdgcn_mfma_f32_16x16x32_bf16(ap1, vb1, oacc[dt], 0,0,0);
    }
    __builtin_amdgcn_s_setprio(0);
    if (it < 15){
      int tok = t>>2, ds = (t&3)*16;
      *(uint4*)&Ks[cur^1][tok][ds]   = pf_k0;
      *(uint4*)&Ks[cur^1][tok][ds+8] = pf_k1;
      *(uint4*)&Vt[cur^1][tok][ds]   = pf_v0;
      *(uint4*)&Vt[cur^1][tok][ds+8] = pf_v1;
      if (t < 64) pk_s[cur^1][t] = pf_p;
    }
    __syncthreads();
  }
  // denominators: quads hold partial sums over their k-slices for q = wid*16+ln
  float l = lsum;
  l += __shfl_xor(l, 16);
  l += __shfl_xor(l, 32);
  #pragma unroll
  for (int r=0;r<4;++r){
    float lr = __shfl(l, quad*4 + r);   // lane quad*4+r holds full sum for q-row ln=quad*4+r
    float inv = 1.f / lr;
    int ql = wid*16 + quad*4 + r;
    long base = (long)(b*1024 + q0 + ql)*512 + h*64;
    #pragma unroll
    for (int dt=0;dt<4;++dt){
      float qh = bfu(q_bf[base + dt*16 + ln]);
      o_bf[base + dt*16 + ln] = f2b(qh + oacc[dt][r]*inv);
    }
  }
}

// ---------------- layernorm (wave per row), bf16 input ----------------
__global__ __launch_bounds__(256) void ln_kernel(
    const unsigned short* in, void* outp, int mode, const float* g, const float* bvec)
{
  const int row = blockIdx.x*4 + (threadIdx.x >> 6);
  const int lane = threadIdx.x & 63;
  uint4 raw = *(const uint4*)(in + (long)row*512 + lane*8);
  const unsigned short* rs16 = (const unsigned short*)&raw;
  float v[8];
  #pragma unroll
  for (int c=0;c<8;++c) v[c] = bfu(rs16[c]);
  float sum = 0.f;
  #pragma unroll
  for (int c=0;c<8;++c) sum += v[c];
  #pragma unroll
  for (int msk=1; msk<64; msk<<=1) sum += __shfl_xor(sum, msk);
  float mu = sum * (1.f/512.f);
  float var = 0.f;
  #pragma unroll
  for (int c=0;c<8;++c){ v[c] -= mu; var += v[c]*v[c]; }
  #pragma unroll
  for (int msk=1; msk<64; msk<<=1) var += __shfl_xor(var, msk);
  float rs = rsqrtf(var*(1.f/512.f) + 1e-5f);
  float gv[8], bv[8];
  *(float4*)&gv[0] = *(const float4*)(g + lane*8);
  *(float4*)&gv[4] = *(const float4*)(g + lane*8 + 4);
  *(float4*)&bv[0] = *(const float4*)(bvec + lane*8);
  *(float4*)&bv[4] = *(const float4*)(bvec + lane*8 + 4);
  float y[8];
  #pragma unroll
  for (int c=0;c<8;++c) y[c] = v[c]*rs*gv[c] + bv[c];
  if (mode){
    float* dst = (float*)outp + (long)row*512 + lane*8;
    *(float4*)dst       = *(float4*)&y[0];
    *(float4*)(dst + 4) = *(float4*)&y[4];
  } else {
    uint4 out; unsigned short* os = (unsigned short*)&out;
    #pragma unroll
    for (int c=0;c<8;++c) os[c] = f2b(y[c]);
    *(uint4*)((unsigned short*)outp + (long)row*512 + lane*8) = out;
  }
}

// ---------------- out projection: u = t + relu(t @ Wo + bo), bf16 out ----------------
__global__ __launch_bounds__(256) void out_mfma(
    const unsigned short* t_bf, const unsigned short* Wt, const float* bo,
    unsigned short* u_bf)
{
  const int row0 = blockIdx.y*64, col0 = blockIdx.x*128;
  __shared__ unsigned short As[2][64][40];
  __shared__ unsigned short Ws[2][128][40];
  const int t = threadIdx.x;
  const int lane = t & 63, wid = t >> 6;
  const int ln = lane & 15, quad = lane >> 4;
  const int wy = wid >> 1, wx = wid & 1;   // wave: 32 rows x 64 cols
  f32x4 acc[2][4];
  #pragma unroll
  for (int i=0;i<2;++i){
    #pragma unroll
    for (int j=0;j<4;++j) acc[i][j] = (f32x4){0.f,0.f,0.f,0.f};
  }
  const int ar = t>>2, ac0 = (t&3)*8;
  const int wr = t>>1, wc0 = (t&1)*16;
  const unsigned short* Arow = t_bf + (long)(row0+ar)*512 + ac0;
  const unsigned short* Wrow = Wt   + (long)(col0+wr)*512 + wc0;
  uint4 a0 = *(const uint4*)(Arow);
  uint4 w0 = *(const uint4*)(Wrow);
  uint4 w1 = *(const uint4*)(Wrow + 8);
  *(uint4*)&As[0][ar][ac0] = a0;
  *(uint4*)&Ws[0][wr][wc0]   = w0;
  *(uint4*)&Ws[0][wr][wc0+8] = w1;
  __syncthreads();
  for (int it=0; it<16; ++it){
    const int cur = it & 1;
    if (it < 15){
      a0 = *(const uint4*)(Arow + (it+1)*32);
      w0 = *(const uint4*)(Wrow + (it+1)*32);
      w1 = *(const uint4*)(Wrow + (it+1)*32 + 8);
    }
    short8 a[2], b[4];
    #pragma unroll
    for (int mt=0;mt<2;++mt) a[mt] = *(const short8*)&As[cur][wy*32+mt*16+ln][quad*8];
    #pragma unroll
    for (int nt=0;nt<4;++nt) b[nt] = *(const short8*)&Ws[cur][wx*64+nt*16+ln][quad*8];
    #pragma unroll
    for (int mt=0;mt<2;++mt){
      #pragma unroll
      for (int nt=0;nt<4;++nt)
        acc[mt][nt] = __builtin_amdgcn_mfma_f32_16x16x32_bf16(a[mt], b[nt], acc[mt][nt], 0,0,0);
    }
    if (it < 15){
      *(uint4*)&As[cur^1][ar][ac0] = a0;
      *(uint4*)&Ws[cur^1][wr][wc0]   = w0;
      *(uint4*)&Ws[cur^1][wr][wc0+8] = w1;
    }
    __syncthreads();
  }
  float bias_v[4];
  #pragma unroll
  for (int nt=0;nt<4;++nt) bias_v[nt] = bo[col0 + wx*64 + nt*16 + ln];
  #pragma unroll
  for (int mt=0;mt<2;++mt){
    int row = row0 + wy*32 + mt*16 + quad*4;
    #pragma unroll
    for (int nt=0;nt<4;++nt){
      int col = col0 + wx*64 + nt*16 + ln;
      #pragma unroll
      for (int r=0;r<4;++r){
        long idx = (long)(row+r)*512 + col;
        float u = acc[mt][nt][r] + bias_v[nt];
        u = fmaxf(u, 0.f);
        u_bf[idx] = f2b(bfu(t_bf[idx]) + u);
      }
    }
  }
}

extern "C" void kernel_launch(void* const* d_in, const int* in_sizes, int n_in,
                              void* d_out, int out_size, void* d_ws, size_t ws_size,
                              hipStream_t stream)
{
  unsigned short* q_bf  = (unsigned short*)d_ws;
  unsigned short* k_bf  = q_bf  + 8192l*512;
  unsigned short* vt_bf = k_bf  + 8192l*512;
  unsigned short* t_bf  = vt_bf + 8192l*512;
  unsigned short* wt    = t_bf  + 8192l*512;
  unsigned short* qin   = wt + 4l*512*512;
  unsigned short* kin   = qin + 4194304;
  unsigned short* o_bf  = qin;   // alias: valid after proj_mfma
  unsigned short* u_bf  = kin;   // alias: valid after proj_mfma

  hipLaunchKernelGGL(prep_inputs, dim3(4352), dim3(256), 0, stream,
                     (const float*)d_in[5], (const float*)d_in[7],
                     (const float*)d_in[9], (const float*)d_in[11],
                     (const float*)d_in[0], (const float*)d_in[1], wt, qin);
  hipLaunchKernelGGL(proj_mfma, dim3(4,64,3), dim3(256), 0, stream,
                     qin, kin, wt,
                     (const float*)d_in[6], (const float*)d_in[8],
                     (const float*)d_in[10], q_bf, k_bf, vt_bf);
  hipLaunchKernelGGL(attn_mfma, dim3(64,16), dim3(256), 0, stream,
                     q_bf, k_bf, vt_bf,
                     (const float*)d_in[2], (const float*)d_in[3], o_bf);
  hipLaunchKernelGGL(ln_kernel, dim3(2048), dim3(256), 0, stream,
                     o_bf, (void*)t_bf, 0, (const float*)d_in[13], (const float*)d_in[14]);
  hipLaunchKernelGGL(out_mfma, dim3(4,128), dim3(256), 0, stream,
                     t_bf, wt + 3l*512*512, (const float*)d_in[12], u_bf);
  hipLaunchKernelGGL(ln_kernel, dim3(2048), dim3(256), 0, stream,
                     u_bf, d_out, 1, (const float*)d_in[15], (const float*)d_in[16]);
}